// Round 1
// baseline (1064.554 us; speedup 1.0000x reference)
//
#include <hip/hip_runtime.h>
#include <hip/hip_bf16.h>
#include <math.h>

#define NATOMS 1280
#define FDIM 64
#define NHEAD 4
#define DHEAD 16
#define EEDGE 5120
#define MKV 12800
#define NLAYERS 4
#define NGRAPH 32
#define NPG 40      // atoms per graph
#define MPG 400     // kv per graph

// ---------------- precompute: EW[l][e][f] = edge_attr @ We[l] ----------------
__global__ void ew_proj_kernel(const float* __restrict__ edge_attr,
                               const float* __restrict__ We,
                               float* __restrict__ EW) {
  int l = blockIdx.y;
  int idx = blockIdx.x * 256 + threadIdx.x;   // e*64 + f
  int e = idx >> 6, f = idx & 63;
  const float* ea = edge_attr + e * 16;
  const float* W = We + l * (16 * 64);
  float acc = 0.f;
#pragma unroll
  for (int k = 0; k < 16; ++k) acc += ea[k] * W[k * 64 + f];
  EW[(long)l * EEDGE * 64 + idx] = acc;
}

// -------- precompute: Kh[l] = K @ Wk[l], Vh[l] = V @ Wv[l]  (all layers) -----
__global__ void kv_proj_kernel(const float* __restrict__ Kin,
                               const float* __restrict__ Vin,
                               const float* __restrict__ Wk,
                               const float* __restrict__ Wv,
                               float* __restrict__ Kh,
                               float* __restrict__ Vh) {
  int t = threadIdx.x;
  int f = t & 63, rr = t >> 6;
  long row = (long)blockIdx.x * 4 + rr;   // layout [which][l][m]
  int m = (int)(row % MKV);
  int tmp = (int)(row / MKV);
  int l = tmp & 3, which = tmp >> 2;
  const float* in = (which ? Vin : Kin) + (long)m * 64;
  const float* W = (which ? Wv : Wk) + l * 4096;
  float* out = (which ? Vh : Kh) + ((long)l * MKV + m) * 64;
  float acc = 0.f;
#pragma unroll 8
  for (int k = 0; k < 64; ++k) acc += in[k] * W[k * 64 + f];
  out[f] = acc;
}

// ------------- per layer: m = silu(x[src] + EW), scatter-add to agg ----------
__global__ void edge_kernel(const float* __restrict__ xin,
                            const float* __restrict__ EWl,
                            const int* __restrict__ src,
                            const int* __restrict__ dst,
                            float* __restrict__ agg) {
  int idx = blockIdx.x * 256 + threadIdx.x;  // e*64 + f
  int e = idx >> 6, f = idx & 63;
  float m = xin[src[e] * 64 + f] + EWl[idx];
  m = m / (1.f + __expf(-m));               // silu
  atomicAdd(&agg[dst[e] * 64 + f], m);
}

// ---- per layer, one block per graph: h, Q, attention, out-proj, residual ----
__global__ __launch_bounds__(512) void layer_kernel(
    const float* __restrict__ xin, const float* __restrict__ agg,
    const float* __restrict__ Wm, const float* __restrict__ Wq,
    const float* __restrict__ Wo, const float* __restrict__ Kh,
    const float* __restrict__ Vh, float* __restrict__ xout) {
  __shared__ float hS[NPG][64];
  __shared__ float qS[NPG][64];
  __shared__ float sS[NPG][MPG];   // 62.5 KiB score buffer (one head at a time)
  __shared__ float oS[NPG][64];

  const int g = blockIdx.x;
  const int t = threadIdx.x;
  const int f = t & 63, qq = t >> 6;        // 8 row-groups of 64 cols
  const int qbase = g * NPG, kbase = g * MPG;

  // stage 1: h = x + agg @ Wm
  for (int q = qq; q < NPG; q += 8) {
    float acc = xin[(qbase + q) * 64 + f];
    const float* arow = agg + (qbase + q) * 64;
#pragma unroll 16
    for (int k = 0; k < 64; ++k) acc += arow[k] * Wm[k * 64 + f];
    hS[q][f] = acc;
  }
  __syncthreads();

  // stage 2: Q = (h @ Wq) * 1/sqrt(D)   (premultiplied 0.25)
  for (int q = qq; q < NPG; q += 8) {
    float acc = 0.f;
#pragma unroll 16
    for (int k = 0; k < 64; ++k) acc += hS[q][k] * Wq[k * 64 + f];
    qS[q][f] = acc * 0.25f;
  }
  __syncthreads();

  // stage 3: attention, one head at a time (S buffer reused)
  for (int hd = 0; hd < NHEAD; ++hd) {
    const int hoff = hd * DHEAD;
    // scores S[q][k] = Qh[q] . Kh[k]
    for (int q = qq; q < NPG; q += 8) {
      for (int k = f; k < MPG; k += 64) {
        const float4* krow =
            reinterpret_cast<const float4*>(Kh + (long)(kbase + k) * 64 + hoff);
        float4 k0 = krow[0], k1 = krow[1], k2 = krow[2], k3 = krow[3];
        float acc = 0.f;
        acc += qS[q][hoff + 0] * k0.x + qS[q][hoff + 1] * k0.y +
               qS[q][hoff + 2] * k0.z + qS[q][hoff + 3] * k0.w;
        acc += qS[q][hoff + 4] * k1.x + qS[q][hoff + 5] * k1.y +
               qS[q][hoff + 6] * k1.z + qS[q][hoff + 7] * k1.w;
        acc += qS[q][hoff + 8] * k2.x + qS[q][hoff + 9] * k2.y +
               qS[q][hoff + 10] * k2.z + qS[q][hoff + 11] * k2.w;
        acc += qS[q][hoff + 12] * k3.x + qS[q][hoff + 13] * k3.y +
               qS[q][hoff + 14] * k3.z + qS[q][hoff + 15] * k3.w;
        sS[q][k] = acc;
      }
    }
    __syncthreads();
    // softmax per row: wave qq handles rows qq, qq+8, ...
    {
      const int lane = f;
      for (int q = qq; q < NPG; q += 8) {
        float mx = -1e30f;
        for (int k = lane; k < MPG; k += 64) mx = fmaxf(mx, sS[q][k]);
        for (int off = 32; off; off >>= 1) mx = fmaxf(mx, __shfl_xor(mx, off));
        float sum = 0.f;
        for (int k = lane; k < MPG; k += 64) {
          float p = __expf(sS[q][k] - mx);
          sS[q][k] = p;
          sum += p;
        }
        for (int off = 32; off; off >>= 1) sum += __shfl_xor(sum, off);
        float inv = 1.0f / sum;
        for (int k = lane; k < MPG; k += 64) sS[q][k] *= inv;
      }
    }
    __syncthreads();
    // O_head = P @ Vh_head : 40x16 outputs
    for (int idx = t; idx < NPG * DHEAD; idx += 512) {
      int q = idx >> 4, d = idx & 15;
      float acc = 0.f;
      for (int k = 0; k < MPG; ++k)
        acc += sS[q][k] * Vh[(long)(kbase + k) * 64 + hoff + d];
      oS[q][hoff + d] = acc;
    }
    __syncthreads();   // before next head reuses sS
  }

  // stage 4: xout = x + O @ Wo
  for (int q = qq; q < NPG; q += 8) {
    float acc = xin[(qbase + q) * 64 + f];
#pragma unroll 16
    for (int k = 0; k < 64; ++k) acc += oS[q][k] * Wo[k * 64 + f];
    xout[(qbase + q) * 64 + f] = acc;
  }
}

extern "C" void kernel_launch(void* const* d_in, const int* in_sizes, int n_in,
                              void* d_out, int out_size, void* d_ws, size_t ws_size,
                              hipStream_t stream) {
  const float* x        = (const float*)d_in[0];
  const float* edge_attr= (const float*)d_in[1];
  const float* K        = (const float*)d_in[2];
  const float* V        = (const float*)d_in[3];
  const float* We       = (const float*)d_in[4];
  const float* Wm       = (const float*)d_in[5];
  const float* Wq       = (const float*)d_in[6];
  const float* Wk       = (const float*)d_in[7];
  const float* Wv       = (const float*)d_in[8];
  const float* Wo       = (const float*)d_in[9];
  const int*   eidx     = (const int*)d_in[10];
  const int*   src      = eidx;
  const int*   dst      = eidx + EEDGE;

  float* w   = (float*)d_ws;
  float* Kh  = w;                        // 4*12800*64
  float* Vh  = Kh + (long)NLAYERS * MKV * 64;
  float* EW  = Vh + (long)NLAYERS * MKV * 64;   // 4*5120*64
  float* agg = EW + (long)NLAYERS * EEDGE * 64; // 1280*64
  float* xA  = agg + NATOMS * 64;
  float* xB  = xA + NATOMS * 64;

  // precompute (independent of x): edge projections + KV projections, all layers
  ew_proj_kernel<<<dim3(EEDGE * 64 / 256, NLAYERS), 256, 0, stream>>>(edge_attr, We, EW);
  kv_proj_kernel<<<(2 * NLAYERS * MKV) / 4, 256, 0, stream>>>(K, V, Wk, Wv, Kh, Vh);

  const float* xin = x;
  for (int l = 0; l < NLAYERS; ++l) {
    hipMemsetAsync(agg, 0, NATOMS * 64 * sizeof(float), stream);
    edge_kernel<<<EEDGE * 64 / 256, 256, 0, stream>>>(
        xin, EW + (long)l * EEDGE * 64, src, dst, agg);
    float* xout = (l == NLAYERS - 1) ? (float*)d_out : ((l & 1) ? xB : xA);
    layer_kernel<<<NGRAPH, 512, 0, stream>>>(
        xin, agg, Wm + l * 4096, Wq + l * 4096, Wo + l * 4096,
        Kh + (long)l * MKV * 64, Vh + (long)l * MKV * 64, xout);
    xin = xout;
  }
}

// Round 2
// 233.607 us; speedup vs baseline: 4.5570x; 4.5570x over previous
//
#include <hip/hip_runtime.h>
#include <hip/hip_bf16.h>
#include <math.h>

#define NATOMS 1280
#define FDIM 64
#define NHEAD 4
#define DHEAD 16
#define EEDGE 5120
#define MKV 12800
#define NLAYERS 4
#define NGRAPH 32
#define NPG 40      // atoms per graph
#define MPG 400     // kv per graph
#define NCHUNK 4
#define CKV 100     // MPG / NCHUNK

// ---------------- precompute: EW[l][e][f] = edge_attr @ We[l] ----------------
__global__ void ew_proj_kernel(const float* __restrict__ edge_attr,
                               const float* __restrict__ We,
                               float* __restrict__ EW) {
  int l = blockIdx.y;
  int idx = blockIdx.x * 256 + threadIdx.x;   // e*64 + f
  int e = idx >> 6, f = idx & 63;
  const float* ea = edge_attr + e * 16;
  const float* W = We + l * (16 * 64);
  float acc = 0.f;
#pragma unroll
  for (int k = 0; k < 16; ++k) acc += ea[k] * W[k * 64 + f];
  EW[(long)l * EEDGE * 64 + idx] = acc;
}

// -------- precompute: Kh[l] = K @ Wk[l], Vh[l] = V @ Wv[l]  (all layers) -----
__global__ void kv_proj_kernel(const float* __restrict__ Kin,
                               const float* __restrict__ Vin,
                               const float* __restrict__ Wk,
                               const float* __restrict__ Wv,
                               float* __restrict__ Kh,
                               float* __restrict__ Vh) {
  int t = threadIdx.x;
  int f = t & 63, rr = t >> 6;
  long row = (long)blockIdx.x * 4 + rr;   // layout [which][l][m]
  int m = (int)(row % MKV);
  int tmp = (int)(row / MKV);
  int l = tmp & 3, which = tmp >> 2;
  const float* in = (which ? Vin : Kin) + (long)m * 64;
  const float* W = (which ? Wv : Wk) + l * 4096;
  float* out = (which ? Vh : Kh) + ((long)l * MKV + m) * 64;
  float acc = 0.f;
#pragma unroll 8
  for (int k = 0; k < 64; ++k) acc += in[k] * W[k * 64 + f];
  out[f] = acc;
}

// ------------- per layer: m = silu(x[src] + EW), scatter-add to agg ----------
__global__ void edge_kernel(const float* __restrict__ xin,
                            const float* __restrict__ EWl,
                            const int* __restrict__ src,
                            const int* __restrict__ dst,
                            float* __restrict__ agg) {
  int idx = blockIdx.x * 256 + threadIdx.x;  // e*64 + f
  int e = idx >> 6, f = idx & 63;
  float m = xin[src[e] * 64 + f] + EWl[idx];
  m = m / (1.f + __expf(-m));               // silu
  atomicAdd(&agg[dst[e] * 64 + f], m);
}

// ------------- per layer: Q = ((x + agg @ Wm) @ Wq) * 1/sqrt(D) --------------
__global__ __launch_bounds__(256) void hq_kernel(
    const float* __restrict__ xin, const float* __restrict__ agg,
    const float* __restrict__ Wm, const float* __restrict__ Wq,
    float* __restrict__ Qout) {
  __shared__ float aS[4][64];
  __shared__ float hS[4][64];
  int t = threadIdx.x;
  int a = t >> 6, f = t & 63;
  int n = blockIdx.x * 4 + a;
  aS[a][f] = agg[n * 64 + f];
  __syncthreads();
  float acc = xin[n * 64 + f];
#pragma unroll 16
  for (int k = 0; k < 64; ++k) acc += aS[a][k] * Wm[k * 64 + f];
  hS[a][f] = acc;
  __syncthreads();
  float q = 0.f;
#pragma unroll 16
  for (int k = 0; k < 64; ++k) q += hS[a][k] * Wq[k * 64 + f];
  Qout[n * 64 + f] = q * 0.25f;
}

// ---- flash-style partial attention: one block per (graph, head, kv-chunk) ---
__global__ __launch_bounds__(256) void attn_part_kernel(
    const float* __restrict__ Q, const float* __restrict__ Kh,
    const float* __restrict__ Vh, float* __restrict__ Apart,
    float* __restrict__ mpart, float* __restrict__ lpart) {
  __shared__ float Qs[NPG][17];
  __shared__ float Kc[CKV][17];
  __shared__ float Vc[CKV][17];
  __shared__ float P[NPG][CKV];
  const int g = blockIdx.x, hd = blockIdx.y, c = blockIdx.z;
  const int t = threadIdx.x;
  const int kbase = g * MPG + c * CKV;
  const int qbase = g * NPG;
  const int hoff = hd * DHEAD;

  for (int i = t; i < NPG * DHEAD; i += 256) {
    int q = i >> 4, d = i & 15;
    Qs[q][d] = Q[(qbase + q) * 64 + hoff + d];
  }
  for (int i = t; i < CKV * DHEAD; i += 256) {
    int r = i >> 4, d = i & 15;
    Kc[r][d] = Kh[(long)(kbase + r) * 64 + hoff + d];
    Vc[r][d] = Vh[(long)(kbase + r) * 64 + hoff + d];
  }
  __syncthreads();

  // scores S[q][k] = Q[q] . K[k]
  for (int i = t; i < NPG * CKV; i += 256) {
    int q = i / CKV, k = i - q * CKV;
    float acc = 0.f;
#pragma unroll
    for (int d = 0; d < DHEAD; ++d) acc += Qs[q][d] * Kc[k][d];
    P[q][k] = acc;
  }
  __syncthreads();

  // per-row max + exp + sum (4 waves, wave w owns rows w, w+4, ...)
  const int w = t >> 6, lane = t & 63;
  for (int q = w; q < NPG; q += 4) {
    float mx = -1e30f;
    for (int k = lane; k < CKV; k += 64) mx = fmaxf(mx, P[q][k]);
    for (int off = 32; off; off >>= 1) mx = fmaxf(mx, __shfl_xor(mx, off));
    float sum = 0.f;
    for (int k = lane; k < CKV; k += 64) {
      float p = __expf(P[q][k] - mx);
      P[q][k] = p;
      sum += p;
    }
    for (int off = 32; off; off >>= 1) sum += __shfl_xor(sum, off);
    if (lane == 0) {
      int o = ((g * NHEAD + hd) * NCHUNK + c) * NPG + q;
      mpart[o] = mx;
      lpart[o] = sum;
    }
  }
  __syncthreads();

  // partial PV (unnormalized)
  float* Ab = Apart + (long)((g * NHEAD + hd) * NCHUNK + c) * NPG * DHEAD;
  for (int i = t; i < NPG * DHEAD; i += 256) {
    int q = i >> 4, d = i & 15;
    float acc = 0.f;
    for (int k = 0; k < CKV; ++k) acc += P[q][k] * Vc[k][d];
    Ab[i] = acc;
  }
}

// ---- combine chunk partials + output projection + residual ------------------
__global__ __launch_bounds__(256) void combine_proj_kernel(
    const float* __restrict__ xin, const float* __restrict__ Apart,
    const float* __restrict__ mpart, const float* __restrict__ lpart,
    const float* __restrict__ Wo, float* __restrict__ xout) {
  __shared__ float oS[4][64];
  int t = threadIdx.x;
  int a = t >> 6, f = t & 63;
  int n = blockIdx.x * 4 + a;
  int g = n / NPG, q = n - g * NPG;
  int hd = f >> 4, d = f & 15;
  int sb = (g * NHEAD + hd) * NCHUNK;
  float mv[NCHUNK];
  float M = -1e30f;
#pragma unroll
  for (int c = 0; c < NCHUNK; ++c) {
    mv[c] = mpart[(sb + c) * NPG + q];
    M = fmaxf(M, mv[c]);
  }
  float denom = 0.f, acc = 0.f;
#pragma unroll
  for (int c = 0; c < NCHUNK; ++c) {
    float wgt = __expf(mv[c] - M);
    denom += lpart[(sb + c) * NPG + q] * wgt;
    acc += Apart[(long)(sb + c) * NPG * DHEAD + q * DHEAD + d] * wgt;
  }
  oS[a][f] = acc / denom;
  __syncthreads();
  float out = xin[n * 64 + f];
#pragma unroll 16
  for (int k = 0; k < 64; ++k) out += oS[a][k] * Wo[k * 64 + f];
  xout[n * 64 + f] = out;
}

extern "C" void kernel_launch(void* const* d_in, const int* in_sizes, int n_in,
                              void* d_out, int out_size, void* d_ws, size_t ws_size,
                              hipStream_t stream) {
  const float* x        = (const float*)d_in[0];
  const float* edge_attr= (const float*)d_in[1];
  const float* K        = (const float*)d_in[2];
  const float* V        = (const float*)d_in[3];
  const float* We       = (const float*)d_in[4];
  const float* Wm       = (const float*)d_in[5];
  const float* Wq       = (const float*)d_in[6];
  const float* Wk       = (const float*)d_in[7];
  const float* Wv       = (const float*)d_in[8];
  const float* Wo       = (const float*)d_in[9];
  const int*   eidx     = (const int*)d_in[10];
  const int*   src      = eidx;
  const int*   dst      = eidx + EEDGE;

  float* w    = (float*)d_ws;
  float* Kh   = w;                                   // 4*12800*64
  float* Vh   = Kh + (long)NLAYERS * MKV * 64;       // 4*12800*64
  float* EW   = Vh + (long)NLAYERS * MKV * 64;       // 4*5120*64
  float* agg  = EW + (long)NLAYERS * EEDGE * 64;     // 4*1280*64
  float* xA   = agg + (long)NLAYERS * NATOMS * 64;
  float* xB   = xA + NATOMS * 64;
  float* Qbuf = xB + NATOMS * 64;                    // 1280*64
  float* Ap   = Qbuf + NATOMS * 64;                  // 32*4*4*40*16
  float* mp   = Ap + (long)NGRAPH * NHEAD * NCHUNK * NPG * DHEAD;
  float* lp   = mp + NGRAPH * NHEAD * NCHUNK * NPG;  // 20480 each

  // zero all per-layer agg buffers once
  hipMemsetAsync(agg, 0, (size_t)NLAYERS * NATOMS * 64 * sizeof(float), stream);
  // precompute (independent of x)
  ew_proj_kernel<<<dim3(EEDGE * 64 / 256, NLAYERS), 256, 0, stream>>>(edge_attr, We, EW);
  kv_proj_kernel<<<(2 * NLAYERS * MKV) / 4, 256, 0, stream>>>(K, V, Wk, Wv, Kh, Vh);

  const float* xin = x;
  for (int l = 0; l < NLAYERS; ++l) {
    float* aggl = agg + (long)l * NATOMS * 64;
    edge_kernel<<<EEDGE * 64 / 256, 256, 0, stream>>>(
        xin, EW + (long)l * EEDGE * 64, src, dst, aggl);
    hq_kernel<<<NATOMS / 4, 256, 0, stream>>>(xin, aggl, Wm + l * 4096,
                                              Wq + l * 4096, Qbuf);
    attn_part_kernel<<<dim3(NGRAPH, NHEAD, NCHUNK), 256, 0, stream>>>(
        Qbuf, Kh + (long)l * MKV * 64, Vh + (long)l * MKV * 64, Ap, mp, lp);
    float* xout = (l == NLAYERS - 1) ? (float*)d_out : ((l & 1) ? xB : xA);
    combine_proj_kernel<<<NATOMS / 4, 256, 0, stream>>>(xin, Ap, mp, lp,
                                                        Wo + l * 4096, xout);
    xin = xout;
  }
}

// Round 3
// 156.452 us; speedup vs baseline: 6.8043x; 1.4932x over previous
//
#include <hip/hip_runtime.h>
#include <hip/hip_bf16.h>
#include <math.h>

#define NATOMS 1280
#define FDIM 64
#define NHEAD 4
#define DHEAD 16
#define EEDGE 5120
#define MKV 12800
#define NLAYERS 4
#define NGRAPH 32
#define NPG 40      // atoms per graph
#define MPG 400     // kv per graph
#define NCHUNK 4
#define CKV 100     // MPG / NCHUNK

// ---- tiled GEMM: Kh[l] = K @ Wk[l], Vh[l] = V @ Wv[l]  (grid.y = which*4+l) --
__global__ __launch_bounds__(256) void kv_gemm_kernel(
    const float* __restrict__ Kin, const float* __restrict__ Vin,
    const float* __restrict__ Wk, const float* __restrict__ Wv,
    float* __restrict__ Kh, float* __restrict__ Vh) {
  __shared__ float aT[64][65];   // A tile transposed [k][row], +1 pad
  __shared__ float wS[64][64];
  const int t = threadIdx.x;
  const int gy = blockIdx.y;
  const int which = gy >> 2, l = gy & 3;
  const float* A = (which ? Vin : Kin) + (size_t)blockIdx.x * 64 * 64;
  const float* W = (which ? Wv : Wk) + l * 4096;
  float* C = (which ? Vh : Kh) + ((size_t)l * MKV + (size_t)blockIdx.x * 64) * 64;

  {  // stage A transposed: thread t loads row r, 16 cols starting at c0
    int r = t >> 2, c0 = (t & 3) * 16;
    const float4* src = reinterpret_cast<const float4*>(A + r * 64 + c0);
#pragma unroll
    for (int u = 0; u < 4; ++u) {
      float4 v = src[u];
      aT[c0 + u * 4 + 0][r] = v.x;
      aT[c0 + u * 4 + 1][r] = v.y;
      aT[c0 + u * 4 + 2][r] = v.z;
      aT[c0 + u * 4 + 3][r] = v.w;
    }
  }
#pragma unroll
  for (int i = t; i < 1024; i += 256) {  // stage W (64x64 = 1024 float4s)
    float4 v = reinterpret_cast<const float4*>(W)[i];
    int row = i >> 4, col = (i & 15) * 4;
    *reinterpret_cast<float4*>(&wS[row][col]) = v;
  }
  __syncthreads();

  const int rb = (t >> 4) * 4, cb = (t & 15) * 4;
  float acc[4][4] = {};
#pragma unroll 8
  for (int k = 0; k < 64; ++k) {
    float4 a = *reinterpret_cast<const float4*>(&aT[k][rb]);
    float4 w = *reinterpret_cast<const float4*>(&wS[k][cb]);
    acc[0][0] += a.x * w.x; acc[0][1] += a.x * w.y; acc[0][2] += a.x * w.z; acc[0][3] += a.x * w.w;
    acc[1][0] += a.y * w.x; acc[1][1] += a.y * w.y; acc[1][2] += a.y * w.z; acc[1][3] += a.y * w.w;
    acc[2][0] += a.z * w.x; acc[2][1] += a.z * w.y; acc[2][2] += a.z * w.z; acc[2][3] += a.z * w.w;
    acc[3][0] += a.w * w.x; acc[3][1] += a.w * w.y; acc[3][2] += a.w * w.z; acc[3][3] += a.w * w.w;
  }
#pragma unroll
  for (int i = 0; i < 4; ++i) {
    float4 o = make_float4(acc[i][0], acc[i][1], acc[i][2], acc[i][3]);
    *reinterpret_cast<float4*>(C + (size_t)(rb + i) * 64 + cb) = o;
  }
}

// ---- tiled GEMM: EW[l] = edge_attr @ We[l]  (K=16), grid.y = layer ----------
__global__ __launch_bounds__(256) void ew_gemm_kernel(
    const float* __restrict__ edge_attr, const float* __restrict__ We,
    float* __restrict__ EW) {
  __shared__ float aT[16][65];
  __shared__ float wS[16][64];
  const int t = threadIdx.x;
  const int l = blockIdx.y;
  const float* A = edge_attr + (size_t)blockIdx.x * 64 * 16;
  const float* W = We + l * 1024;
  float* C = EW + ((size_t)l * EEDGE + (size_t)blockIdx.x * 64) * 64;

  {  // stage A transposed (64 rows x 16 cols)
    int r = t >> 2, c0 = (t & 3) * 4;
    float4 v = *reinterpret_cast<const float4*>(A + r * 16 + c0);
    aT[c0 + 0][r] = v.x;
    aT[c0 + 1][r] = v.y;
    aT[c0 + 2][r] = v.z;
    aT[c0 + 3][r] = v.w;
  }
  {  // stage W (16x64 = 256 float4s)
    float4 v = reinterpret_cast<const float4*>(W)[t];
    int row = t >> 4, col = (t & 15) * 4;
    *reinterpret_cast<float4*>(&wS[row][col]) = v;
  }
  __syncthreads();

  const int rb = (t >> 4) * 4, cb = (t & 15) * 4;
  float acc[4][4] = {};
#pragma unroll
  for (int k = 0; k < 16; ++k) {
    float4 a = *reinterpret_cast<const float4*>(&aT[k][rb]);
    float4 w = *reinterpret_cast<const float4*>(&wS[k][cb]);
    acc[0][0] += a.x * w.x; acc[0][1] += a.x * w.y; acc[0][2] += a.x * w.z; acc[0][3] += a.x * w.w;
    acc[1][0] += a.y * w.x; acc[1][1] += a.y * w.y; acc[1][2] += a.y * w.z; acc[1][3] += a.y * w.w;
    acc[2][0] += a.z * w.x; acc[2][1] += a.z * w.y; acc[2][2] += a.z * w.z; acc[2][3] += a.z * w.w;
    acc[3][0] += a.w * w.x; acc[3][1] += a.w * w.y; acc[3][2] += a.w * w.z; acc[3][3] += a.w * w.w;
  }
#pragma unroll
  for (int i = 0; i < 4; ++i) {
    float4 o = make_float4(acc[i][0], acc[i][1], acc[i][2], acc[i][3]);
    *reinterpret_cast<float4*>(C + (size_t)(rb + i) * 64 + cb) = o;
  }
}

// ------------- per layer: m = silu(x[src] + EW), scatter-add to agg ----------
__global__ void edge_kernel(const float* __restrict__ xin,
                            const float* __restrict__ EWl,
                            const int* __restrict__ src,
                            const int* __restrict__ dst,
                            float* __restrict__ agg) {
  int idx = blockIdx.x * 256 + threadIdx.x;  // e*64 + f
  int e = idx >> 6, f = idx & 63;
  float m = xin[src[e] * 64 + f] + EWl[idx];
  m = m / (1.f + __expf(-m));               // silu
  atomicAdd(&agg[dst[e] * 64 + f], m);
}

// ------------- per layer: Q = ((x + agg @ Wm) @ Wq) * 1/sqrt(D) --------------
__global__ __launch_bounds__(256) void hq_kernel(
    const float* __restrict__ xin, const float* __restrict__ agg,
    const float* __restrict__ Wm, const float* __restrict__ Wq,
    float* __restrict__ Qout) {
  __shared__ float aS[4][64];
  __shared__ float hS[4][64];
  int t = threadIdx.x;
  int a = t >> 6, f = t & 63;
  int n = blockIdx.x * 4 + a;
  aS[a][f] = agg[n * 64 + f];
  __syncthreads();
  float acc = xin[n * 64 + f];
#pragma unroll 16
  for (int k = 0; k < 64; ++k) acc += aS[a][k] * Wm[k * 64 + f];
  hS[a][f] = acc;
  __syncthreads();
  float q = 0.f;
#pragma unroll 16
  for (int k = 0; k < 64; ++k) q += hS[a][k] * Wq[k * 64 + f];
  Qout[n * 64 + f] = q * 0.25f;
}

// ---- flash-style partial attention: one block per (graph, head, kv-chunk) ---
__global__ __launch_bounds__(256) void attn_part_kernel(
    const float* __restrict__ Q, const float* __restrict__ Kh,
    const float* __restrict__ Vh, float* __restrict__ Apart,
    float* __restrict__ mpart, float* __restrict__ lpart) {
  __shared__ float Qs[NPG][17];
  __shared__ float Kc[CKV][17];
  __shared__ float Vc[CKV][17];
  __shared__ float P[NPG][CKV];
  const int g = blockIdx.x, hd = blockIdx.y, c = blockIdx.z;
  const int t = threadIdx.x;
  const int kbase = g * MPG + c * CKV;
  const int qbase = g * NPG;
  const int hoff = hd * DHEAD;

  for (int i = t; i < NPG * DHEAD; i += 256) {
    int q = i >> 4, d = i & 15;
    Qs[q][d] = Q[(qbase + q) * 64 + hoff + d];
  }
  for (int i = t; i < CKV * DHEAD; i += 256) {
    int r = i >> 4, d = i & 15;
    Kc[r][d] = Kh[(long)(kbase + r) * 64 + hoff + d];
    Vc[r][d] = Vh[(long)(kbase + r) * 64 + hoff + d];
  }
  __syncthreads();

  // scores S[q][k] = Q[q] . K[k]
  for (int i = t; i < NPG * CKV; i += 256) {
    int q = i / CKV, k = i - q * CKV;
    float acc = 0.f;
#pragma unroll
    for (int d = 0; d < DHEAD; ++d) acc += Qs[q][d] * Kc[k][d];
    P[q][k] = acc;
  }
  __syncthreads();

  // per-row max + exp + sum (4 waves, wave w owns rows w, w+4, ...)
  const int w = t >> 6, lane = t & 63;
  for (int q = w; q < NPG; q += 4) {
    float mx = -1e30f;
    for (int k = lane; k < CKV; k += 64) mx = fmaxf(mx, P[q][k]);
    for (int off = 32; off; off >>= 1) mx = fmaxf(mx, __shfl_xor(mx, off));
    float sum = 0.f;
    for (int k = lane; k < CKV; k += 64) {
      float p = __expf(P[q][k] - mx);
      P[q][k] = p;
      sum += p;
    }
    for (int off = 32; off; off >>= 1) sum += __shfl_xor(sum, off);
    if (lane == 0) {
      int o = ((g * NHEAD + hd) * NCHUNK + c) * NPG + q;
      mpart[o] = mx;
      lpart[o] = sum;
    }
  }
  __syncthreads();

  // partial PV (unnormalized)
  float* Ab = Apart + (long)((g * NHEAD + hd) * NCHUNK + c) * NPG * DHEAD;
  for (int i = t; i < NPG * DHEAD; i += 256) {
    int q = i >> 4, d = i & 15;
    float acc = 0.f;
    for (int k = 0; k < CKV; ++k) acc += P[q][k] * Vc[k][d];
    Ab[i] = acc;
  }
}

// ---- combine chunk partials + output projection + residual ------------------
__global__ __launch_bounds__(256) void combine_proj_kernel(
    const float* __restrict__ xin, const float* __restrict__ Apart,
    const float* __restrict__ mpart, const float* __restrict__ lpart,
    const float* __restrict__ Wo, float* __restrict__ xout) {
  __shared__ float oS[4][64];
  int t = threadIdx.x;
  int a = t >> 6, f = t & 63;
  int n = blockIdx.x * 4 + a;
  int g = n / NPG, q = n - g * NPG;
  int hd = f >> 4, d = f & 15;
  int sb = (g * NHEAD + hd) * NCHUNK;
  float mv[NCHUNK];
  float M = -1e30f;
#pragma unroll
  for (int c = 0; c < NCHUNK; ++c) {
    mv[c] = mpart[(sb + c) * NPG + q];
    M = fmaxf(M, mv[c]);
  }
  float denom = 0.f, acc = 0.f;
#pragma unroll
  for (int c = 0; c < NCHUNK; ++c) {
    float wgt = __expf(mv[c] - M);
    denom += lpart[(sb + c) * NPG + q] * wgt;
    acc += Apart[(long)(sb + c) * NPG * DHEAD + q * DHEAD + d] * wgt;
  }
  oS[a][f] = acc / denom;
  __syncthreads();
  float out = xin[n * 64 + f];
#pragma unroll 16
  for (int k = 0; k < 64; ++k) out += oS[a][k] * Wo[k * 64 + f];
  xout[n * 64 + f] = out;
}

extern "C" void kernel_launch(void* const* d_in, const int* in_sizes, int n_in,
                              void* d_out, int out_size, void* d_ws, size_t ws_size,
                              hipStream_t stream) {
  const float* x        = (const float*)d_in[0];
  const float* edge_attr= (const float*)d_in[1];
  const float* K        = (const float*)d_in[2];
  const float* V        = (const float*)d_in[3];
  const float* We       = (const float*)d_in[4];
  const float* Wm       = (const float*)d_in[5];
  const float* Wq       = (const float*)d_in[6];
  const float* Wk       = (const float*)d_in[7];
  const float* Wv       = (const float*)d_in[8];
  const float* Wo       = (const float*)d_in[9];
  const int*   eidx     = (const int*)d_in[10];
  const int*   src      = eidx;
  const int*   dst      = eidx + EEDGE;

  float* w    = (float*)d_ws;
  float* Kh   = w;                                   // 4*12800*64
  float* Vh   = Kh + (long)NLAYERS * MKV * 64;       // 4*12800*64
  float* EW   = Vh + (long)NLAYERS * MKV * 64;       // 4*5120*64
  float* agg  = EW + (long)NLAYERS * EEDGE * 64;     // 4*1280*64
  float* xA   = agg + (long)NLAYERS * NATOMS * 64;
  float* xB   = xA + NATOMS * 64;
  float* Qbuf = xB + NATOMS * 64;                    // 1280*64
  float* Ap   = Qbuf + NATOMS * 64;                  // 32*4*4*40*16
  float* mp   = Ap + (long)NGRAPH * NHEAD * NCHUNK * NPG * DHEAD;
  float* lp   = mp + NGRAPH * NHEAD * NCHUNK * NPG;  // 20480 each

  // zero all per-layer agg buffers once
  hipMemsetAsync(agg, 0, (size_t)NLAYERS * NATOMS * 64 * sizeof(float), stream);
  // precompute (independent of x)
  ew_gemm_kernel<<<dim3(EEDGE / 64, NLAYERS), 256, 0, stream>>>(edge_attr, We, EW);
  kv_gemm_kernel<<<dim3(MKV / 64, 8), 256, 0, stream>>>(K, V, Wk, Wv, Kh, Vh);

  const float* xin = x;
  for (int l = 0; l < NLAYERS; ++l) {
    float* aggl = agg + (long)l * NATOMS * 64;
    edge_kernel<<<EEDGE * 64 / 256, 256, 0, stream>>>(
        xin, EW + (long)l * EEDGE * 64, src, dst, aggl);
    hq_kernel<<<NATOMS / 4, 256, 0, stream>>>(xin, aggl, Wm + l * 4096,
                                              Wq + l * 4096, Qbuf);
    attn_part_kernel<<<dim3(NGRAPH, NHEAD, NCHUNK), 256, 0, stream>>>(
        Qbuf, Kh + (long)l * MKV * 64, Vh + (long)l * MKV * 64, Ap, mp, lp);
    float* xout = (l == NLAYERS - 1) ? (float*)d_out : ((l & 1) ? xB : xA);
    combine_proj_kernel<<<NATOMS / 4, 256, 0, stream>>>(xin, Ap, mp, lp,
                                                        Wo + l * 4096, xout);
    xin = xout;
  }
}

// Round 4
// 143.367 us; speedup vs baseline: 7.4254x; 1.0913x over previous
//
#include <hip/hip_runtime.h>
#include <hip/hip_bf16.h>
#include <math.h>

#define NATOMS 1280
#define FDIM 64
#define NHEAD 4
#define DHEAD 16
#define EEDGE 5120
#define MKV 12800
#define NLAYERS 4
#define NGRAPH 32
#define NPG 40      // atoms per graph
#define MPG 400     // kv per graph
#define QH 20       // q rows per block (half graph)

// ---- tiled GEMM: Kh[l] = K @ Wk[l], Vh[l] = V @ Wv[l]; 128-row tiles --------
__global__ __launch_bounds__(256) void kv_gemm_kernel(
    const float* __restrict__ Kin, const float* __restrict__ Vin,
    const float* __restrict__ Wk, const float* __restrict__ Wv,
    float* __restrict__ Kh, float* __restrict__ Vh) {
  __shared__ float aT[64][132];  // A tile transposed [k][row], pad to 132
  __shared__ float wS[64][64];
  const int t = threadIdx.x;
  const int gy = blockIdx.y;
  const int which = gy >> 2, l = gy & 3;
  const float* A = (which ? Vin : Kin) + (size_t)blockIdx.x * 128 * 64;
  const float* W = (which ? Wv : Wk) + l * 4096;
  float* C = (which ? Vh : Kh) + ((size_t)l * MKV + (size_t)blockIdx.x * 128) * 64;

  for (int i = t; i < 2048; i += 256) {  // 128 rows x 16 float4
    int r = i >> 4, c0 = (i & 15) * 4;
    float4 v = *reinterpret_cast<const float4*>(A + r * 64 + c0);
    aT[c0 + 0][r] = v.x;
    aT[c0 + 1][r] = v.y;
    aT[c0 + 2][r] = v.z;
    aT[c0 + 3][r] = v.w;
  }
  for (int i = t; i < 1024; i += 256) {  // W: 64x64 = 1024 float4
    float4 v = reinterpret_cast<const float4*>(W)[i];
    int row = i >> 4, col = (i & 15) * 4;
    *reinterpret_cast<float4*>(&wS[row][col]) = v;
  }
  __syncthreads();

  const int rb = (t >> 4) * 8, cb = (t & 15) * 4;
  float acc[8][4] = {};
#pragma unroll 4
  for (int k = 0; k < 64; ++k) {
    float4 a0 = *reinterpret_cast<const float4*>(&aT[k][rb]);
    float4 a1 = *reinterpret_cast<const float4*>(&aT[k][rb + 4]);
    float4 w = *reinterpret_cast<const float4*>(&wS[k][cb]);
    acc[0][0] += a0.x * w.x; acc[0][1] += a0.x * w.y; acc[0][2] += a0.x * w.z; acc[0][3] += a0.x * w.w;
    acc[1][0] += a0.y * w.x; acc[1][1] += a0.y * w.y; acc[1][2] += a0.y * w.z; acc[1][3] += a0.y * w.w;
    acc[2][0] += a0.z * w.x; acc[2][1] += a0.z * w.y; acc[2][2] += a0.z * w.z; acc[2][3] += a0.z * w.w;
    acc[3][0] += a0.w * w.x; acc[3][1] += a0.w * w.y; acc[3][2] += a0.w * w.z; acc[3][3] += a0.w * w.w;
    acc[4][0] += a1.x * w.x; acc[4][1] += a1.x * w.y; acc[4][2] += a1.x * w.z; acc[4][3] += a1.x * w.w;
    acc[5][0] += a1.y * w.x; acc[5][1] += a1.y * w.y; acc[5][2] += a1.y * w.z; acc[5][3] += a1.y * w.w;
    acc[6][0] += a1.z * w.x; acc[6][1] += a1.z * w.y; acc[6][2] += a1.z * w.z; acc[6][3] += a1.z * w.w;
    acc[7][0] += a1.w * w.x; acc[7][1] += a1.w * w.y; acc[7][2] += a1.w * w.z; acc[7][3] += a1.w * w.w;
  }
#pragma unroll
  for (int i = 0; i < 8; ++i) {
    float4 o = make_float4(acc[i][0], acc[i][1], acc[i][2], acc[i][3]);
    *reinterpret_cast<float4*>(C + (size_t)(rb + i) * 64 + cb) = o;
  }
}

// ---- tiled GEMM: EW[l] = edge_attr @ We[l]  (K=16), grid.y = layer ----------
__global__ __launch_bounds__(256) void ew_gemm_kernel(
    const float* __restrict__ edge_attr, const float* __restrict__ We,
    float* __restrict__ EW) {
  __shared__ float aT[16][65];
  __shared__ float wS[16][64];
  const int t = threadIdx.x;
  const int l = blockIdx.y;
  const float* A = edge_attr + (size_t)blockIdx.x * 64 * 16;
  const float* W = We + l * 1024;
  float* C = EW + ((size_t)l * EEDGE + (size_t)blockIdx.x * 64) * 64;

  {
    int r = t >> 2, c0 = (t & 3) * 4;
    float4 v = *reinterpret_cast<const float4*>(A + r * 16 + c0);
    aT[c0 + 0][r] = v.x;
    aT[c0 + 1][r] = v.y;
    aT[c0 + 2][r] = v.z;
    aT[c0 + 3][r] = v.w;
  }
  {
    float4 v = reinterpret_cast<const float4*>(W)[t];
    int row = t >> 4, col = (t & 15) * 4;
    *reinterpret_cast<float4*>(&wS[row][col]) = v;
  }
  __syncthreads();

  const int rb = (t >> 4) * 4, cb = (t & 15) * 4;
  float acc[4][4] = {};
#pragma unroll
  for (int k = 0; k < 16; ++k) {
    float4 a = *reinterpret_cast<const float4*>(&aT[k][rb]);
    float4 w = *reinterpret_cast<const float4*>(&wS[k][cb]);
    acc[0][0] += a.x * w.x; acc[0][1] += a.x * w.y; acc[0][2] += a.x * w.z; acc[0][3] += a.x * w.w;
    acc[1][0] += a.y * w.x; acc[1][1] += a.y * w.y; acc[1][2] += a.y * w.z; acc[1][3] += a.y * w.w;
    acc[2][0] += a.z * w.x; acc[2][1] += a.z * w.y; acc[2][2] += a.z * w.z; acc[2][3] += a.z * w.w;
    acc[3][0] += a.w * w.x; acc[3][1] += a.w * w.y; acc[3][2] += a.w * w.z; acc[3][3] += a.w * w.w;
  }
#pragma unroll
  for (int i = 0; i < 4; ++i) {
    float4 o = make_float4(acc[i][0], acc[i][1], acc[i][2], acc[i][3]);
    *reinterpret_cast<float4*>(C + (size_t)(rb + i) * 64 + cb) = o;
  }
}

// -- per layer: edge messages + scatter-add, AND init xout = xin (residual) ---
__global__ void edge_copy_kernel(const float* __restrict__ xin,
                                 const float* __restrict__ EWl,
                                 const int* __restrict__ src,
                                 const int* __restrict__ dst,
                                 float* __restrict__ agg,
                                 float* __restrict__ xout) {
  int idx = blockIdx.x * 256 + threadIdx.x;  // covers E*64 = 327680
  if (idx < NATOMS * 64) xout[idx] = xin[idx];
  int e = idx >> 6, f = idx & 63;
  float m = xin[src[e] * 64 + f] + EWl[idx];
  m = m / (1.f + __expf(-m));  // silu
  atomicAdd(&agg[dst[e] * 64 + f], m);
}

// -- fused: h = x+agg@Wm, Q=h@Wq*s, full 400-KV softmax, PV, o@Wo -> atomicAdd
//    one block per (graph, head, q-half): 32*4*2 = 256 blocks x 512 threads ---
__global__ __launch_bounds__(512) void fused_attn_kernel(
    const float* __restrict__ xin, const float* __restrict__ agg,
    const float* __restrict__ Wm, const float* __restrict__ Wq,
    const float* __restrict__ Wo, const float* __restrict__ Kh,
    const float* __restrict__ Vh, float* __restrict__ xout) {
  __shared__ float aggS[QH][64];   // 5 KB
  __shared__ float hS[QH][64];     // 5 KB
  __shared__ float Qs[QH][16];     // 1.25 KB
  __shared__ float KV[MPG][20];    // 31.25 KB (K then V)
  __shared__ float P[QH][MPG];     // 31.25 KB
  __shared__ float oS[QH][16];     // 1.25 KB
  __shared__ float lsum[QH];

  const int g = blockIdx.x, hd = blockIdx.y, qh = blockIdx.z;
  const int t = threadIdx.x;
  const int hoff = hd * DHEAD;
  const int qbase = g * NPG + qh * QH;
  const int kbase = g * MPG;

  // stage agg rows for this q-half
  for (int i = t; i < QH * 64; i += 512)
    aggS[i >> 6][i & 63] = agg[(qbase + (i >> 6)) * 64 + (i & 63)];
  __syncthreads();

  // h = xin + aggS @ Wm
  for (int i = t; i < QH * 64; i += 512) {
    int q = i >> 6, f = i & 63;
    float acc = xin[(qbase + q) * 64 + f];
#pragma unroll 16
    for (int k = 0; k < 64; ++k) acc += aggS[q][k] * Wm[k * 64 + f];
    hS[q][f] = acc;
  }
  __syncthreads();

  // Q_head = (h @ Wq[:, hoff:hoff+16]) * 0.25
  for (int i = t; i < QH * 16; i += 512) {
    int q = i >> 4, d = i & 15;
    float acc = 0.f;
#pragma unroll 16
    for (int k = 0; k < 64; ++k) acc += hS[q][k] * Wq[k * 64 + hoff + d];
    Qs[q][d] = acc * 0.25f;
  }
  // stage K head-slice [400][16] (KV region untouched so far)
  for (int i = t; i < MPG * DHEAD; i += 512) {
    int r = i >> 4, d = i & 15;
    KV[r][d] = Kh[(size_t)(kbase + r) * 64 + hoff + d];
  }
  __syncthreads();

  // scores P[q][k] = Q[q] . K[k]
  for (int i = t; i < QH * MPG; i += 512) {
    int q = i / MPG, k = i - q * MPG;
    float4 q0 = *reinterpret_cast<const float4*>(&Qs[q][0]);
    float4 q1 = *reinterpret_cast<const float4*>(&Qs[q][4]);
    float4 q2 = *reinterpret_cast<const float4*>(&Qs[q][8]);
    float4 q3 = *reinterpret_cast<const float4*>(&Qs[q][12]);
    float4 k0 = *reinterpret_cast<const float4*>(&KV[k][0]);
    float4 k1 = *reinterpret_cast<const float4*>(&KV[k][4]);
    float4 k2 = *reinterpret_cast<const float4*>(&KV[k][8]);
    float4 k3 = *reinterpret_cast<const float4*>(&KV[k][12]);
    float acc = q0.x * k0.x + q0.y * k0.y + q0.z * k0.z + q0.w * k0.w +
                q1.x * k1.x + q1.y * k1.y + q1.z * k1.z + q1.w * k1.w +
                q2.x * k2.x + q2.y * k2.y + q2.z * k2.z + q2.w * k2.w +
                q3.x * k3.x + q3.y * k3.y + q3.z * k3.z + q3.w * k3.w;
    P[q][k] = acc;
  }
  __syncthreads();

  // stage V head-slice over K (scores done reading K)
  for (int i = t; i < MPG * DHEAD; i += 512) {
    int r = i >> 4, d = i & 15;
    KV[r][d] = Vh[(size_t)(kbase + r) * 64 + hoff + d];
  }
  // softmax rows (raw exp + row sums); 8 waves, rows strided
  {
    const int w = t >> 6, lane = t & 63;
    for (int q = w; q < QH; q += 8) {
      float mx = -1e30f;
      for (int k = lane; k < MPG; k += 64) mx = fmaxf(mx, P[q][k]);
      for (int off = 32; off; off >>= 1) mx = fmaxf(mx, __shfl_xor(mx, off));
      float sum = 0.f;
      for (int k = lane; k < MPG; k += 64) {
        float p = __expf(P[q][k] - mx);
        P[q][k] = p;
        sum += p;
      }
      for (int off = 32; off; off >>= 1) sum += __shfl_xor(sum, off);
      if (lane == 0) lsum[q] = sum;
    }
  }
  __syncthreads();

  // PV: o[q][d] = (sum_k P[q][k] * V[k][d]) / lsum[q]
  if (t < QH * 16) {
    int q = t >> 4, d = t & 15;
    float acc = 0.f;
    for (int k = 0; k < MPG; k += 4) {
      float4 p = *reinterpret_cast<const float4*>(&P[q][k]);
      acc += p.x * KV[k][d] + p.y * KV[k + 1][d] + p.z * KV[k + 2][d] +
             p.w * KV[k + 3][d];
    }
    oS[q][d] = acc / lsum[q];
  }
  __syncthreads();

  // out-proj partial for this head: xout += oS @ Wo[hoff:hoff+16, :]
  for (int i = t; i < QH * 64; i += 512) {
    int q = i >> 6, f = i & 63;
    float acc = 0.f;
#pragma unroll
    for (int d = 0; d < DHEAD; ++d) acc += oS[q][d] * Wo[(hoff + d) * 64 + f];
    atomicAdd(&xout[(qbase + q) * 64 + f], acc);
  }
}

extern "C" void kernel_launch(void* const* d_in, const int* in_sizes, int n_in,
                              void* d_out, int out_size, void* d_ws, size_t ws_size,
                              hipStream_t stream) {
  const float* x        = (const float*)d_in[0];
  const float* edge_attr= (const float*)d_in[1];
  const float* K        = (const float*)d_in[2];
  const float* V        = (const float*)d_in[3];
  const float* We       = (const float*)d_in[4];
  const float* Wm       = (const float*)d_in[5];
  const float* Wq       = (const float*)d_in[6];
  const float* Wk       = (const float*)d_in[7];
  const float* Wv       = (const float*)d_in[8];
  const float* Wo       = (const float*)d_in[9];
  const int*   eidx     = (const int*)d_in[10];
  const int*   src      = eidx;
  const int*   dst      = eidx + EEDGE;

  float* w    = (float*)d_ws;
  float* Kh   = w;                                   // 4*12800*64
  float* Vh   = Kh + (size_t)NLAYERS * MKV * 64;     // 4*12800*64
  float* EW   = Vh + (size_t)NLAYERS * MKV * 64;     // 4*5120*64
  float* agg  = EW + (size_t)NLAYERS * EEDGE * 64;   // 4*1280*64
  float* xA   = agg + (size_t)NLAYERS * NATOMS * 64;
  float* xB   = xA + NATOMS * 64;

  // zero all per-layer agg buffers once
  hipMemsetAsync(agg, 0, (size_t)NLAYERS * NATOMS * 64 * sizeof(float), stream);
  // precompute (independent of x)
  ew_gemm_kernel<<<dim3(EEDGE / 64, NLAYERS), 256, 0, stream>>>(edge_attr, We, EW);
  kv_gemm_kernel<<<dim3(MKV / 128, 8), 256, 0, stream>>>(K, V, Wk, Wv, Kh, Vh);

  const float* xin = x;
  for (int l = 0; l < NLAYERS; ++l) {
    float* aggl = agg + (size_t)l * NATOMS * 64;
    float* xout = (l == NLAYERS - 1) ? (float*)d_out : ((l & 1) ? xB : xA);
    edge_copy_kernel<<<EEDGE * 64 / 256, 256, 0, stream>>>(
        xin, EW + (size_t)l * EEDGE * 64, src, dst, aggl, xout);
    fused_attn_kernel<<<dim3(NGRAPH, NHEAD, 2), 512, 0, stream>>>(
        xin, aggl, Wm + l * 4096, Wq + l * 4096, Wo + l * 4096,
        Kh + (size_t)l * MKV * 64, Vh + (size_t)l * MKV * 64, xout);
    xin = xout;
  }
}